// Round 2
// baseline (99.264 us; speedup 1.0000x reference)
//
#include <hip/hip_runtime.h>
#include <hip/hip_bf16.h>

#define NPTS   300
#define HW_SZ  1920
#define NH     8
#define ED2    128               // EMBED_DIM / 2
#define TOTAL  (NPTS * HW_SZ)    // 576000
#define BLK    256

// f(delta) lookup table: 32768 entries over [-16, 16], h = 2^-10.
// delta = log((relu(pd)+eps)/(dm+eps)) is bounded by ±ln(6e6) = ±15.61.
#define TBL_N    32768
#define TBL_LO   (-16.0f)
#define TBL_H    (1.0f / 1024.0f)
#define TBL_INVH 1024.0f
#define CHUNKS   8               // frequency chunks per table entry
#define EPB      (BLK / CHUNKS)  // table entries per block = 32
#define IPC      (ED2 / CHUNKS)  // freq iterations per chunk  = 16

// Build tbl[e][h] = b[h] + sum_i Ws[i,h] sin(k_i d_e) + Wc[i,h] cos(k_i d_e)
// Parallelized over (entry, freq-chunk); LDS reduction across chunks.
__global__ __launch_bounds__(BLK) void dre_build(const float* __restrict__ W,
                                                 const float* __restrict__ b,
                                                 float* __restrict__ tbl)
{
    __shared__ float kf[ED2];
    __shared__ float red[BLK * NH];   // 8 KB
    const int tid = threadIdx.x;
    if (tid < ED2)
        kf[tid] = 100.0f * exp2f(-(float)tid * (float)(13.287712379549449 / 128.0));
    __syncthreads();

    const int el = tid >> 3;          // entry within block, 0..31
    const int c  = tid & 7;           // freq chunk, 0..7
    const int entry = blockIdx.x * EPB + el;
    const float delta = TBL_LO + (float)entry * TBL_H;

    float acc[NH];
#pragma unroll
    for (int h = 0; h < NH; ++h) acc[h] = 0.0f;

    const int i0 = c * IPC;
#pragma unroll
    for (int ii = 0; ii < IPC; ++ii) {
        const int i = i0 + ii;
        const float a = delta * kf[i];
        const float s  = __sinf(a);
        const float cc = __cosf(a);
        const float* wr = W + i * 2 * NH;
#pragma unroll
        for (int h = 0; h < NH; ++h) {
            acc[h] = fmaf(s,  wr[h],      acc[h]);
            acc[h] = fmaf(cc, wr[NH + h], acc[h]);
        }
    }
#pragma unroll
    for (int h = 0; h < NH; ++h) red[tid * NH + h] = acc[h];
    __syncthreads();

    // reduce 8 chunks; one (entry, head) per thread: 32*8 = 256 exactly
    const int e2 = tid >> 3, h2 = tid & 7;
    float sum = 0.0f;
#pragma unroll
    for (int c2 = 0; c2 < CHUNKS; ++c2)
        sum += red[(e2 * CHUNKS + c2) * NH + h2];
    tbl[(size_t)(blockIdx.x * EPB + e2) * NH + h2] = sum + b[h2];
}

// Main: one thread per 4 consecutive hw points. delta -> lerp(table) -> relu.
__global__ __launch_bounds__(BLK) void dre_main(const float* __restrict__ pd,
                                                const float* __restrict__ dm,
                                                const float* __restrict__ tbl,
                                                float* __restrict__ out)
{
    const int g = blockIdx.x * BLK + threadIdx.x;
    const int p = g * 4;
    if (p >= TOTAL) return;
    const int n  = p / HW_SZ;
    const int hw = p - n * HW_SZ;     // multiple of 4, same n for all 4 pts

    const float lp = __logf(fmaxf(pd[n], 0.0f) + 1e-5f);
    const float4 dv = *(const float4*)(dm + hw);
    const float dvs[4] = {dv.x, dv.y, dv.z, dv.w};

    float vout[4][NH];
#pragma unroll
    for (int q = 0; q < 4; ++q) {
        const float delta = lp - __logf(dvs[q] + 1e-5f);
        const float t  = (delta - TBL_LO) * TBL_INVH;
        const float jf = floorf(t);
        int j = (int)jf;
        j = max(0, min(j, TBL_N - 2));
        const float f = t - jf;
        const float4* row = (const float4*)(tbl + (size_t)j * NH);  // 32B-aligned
        const float4 a0 = row[0], a1 = row[1];   // row j
        const float4 b0 = row[2], b1 = row[3];   // row j+1
        vout[q][0] = fmaxf(fmaf(f, b0.x - a0.x, a0.x), 0.0f);
        vout[q][1] = fmaxf(fmaf(f, b0.y - a0.y, a0.y), 0.0f);
        vout[q][2] = fmaxf(fmaf(f, b0.z - a0.z, a0.z), 0.0f);
        vout[q][3] = fmaxf(fmaf(f, b0.w - a0.w, a0.w), 0.0f);
        vout[q][4] = fmaxf(fmaf(f, b1.x - a1.x, a1.x), 0.0f);
        vout[q][5] = fmaxf(fmaf(f, b1.y - a1.y, a1.y), 0.0f);
        vout[q][6] = fmaxf(fmaf(f, b1.z - a1.z, a1.z), 0.0f);
        vout[q][7] = fmaxf(fmaf(f, b1.w - a1.w, a1.w), 0.0f);
    }

#pragma unroll
    for (int h = 0; h < NH; ++h) {
        float4 o = make_float4(vout[0][h], vout[1][h], vout[2][h], vout[3][h]);
        *(float4*)(out + (size_t)h * TOTAL + p) = o;   // p%4==0 -> 16B aligned
    }
}

extern "C" void kernel_launch(void* const* d_in, const int* in_sizes, int n_in,
                              void* d_out, int out_size, void* d_ws, size_t ws_size,
                              hipStream_t stream) {
    const float* pd = (const float*)d_in[0];
    const float* dm = (const float*)d_in[1];
    const float* W  = (const float*)d_in[2];
    const float* b  = (const float*)d_in[3];
    float* out = (float*)d_out;
    float* tbl = (float*)d_ws;    // needs TBL_N*NH*4 = 1 MB of ws

    dre_build<<<TBL_N / EPB, BLK, 0, stream>>>(W, b, tbl);
    dre_main<<<(TOTAL / 4 + BLK - 1) / BLK, BLK, 0, stream>>>(pd, dm, tbl, out);
}

// Round 3
// 87.161 us; speedup vs baseline: 1.1389x; 1.1389x over previous
//
#include <hip/hip_runtime.h>
#include <hip/hip_bf16.h>

#define NPTS   300
#define HW_SZ  1920
#define NH     8
#define TOTAL  (NPTS * HW_SZ)    // 576000
#define BLK    256

// f(delta) lookup table: 32768 bf16 rows (8 heads, 16 B) over [-16, 16], h = 2^-10.
// |delta| = |log((relu(pd)+1e-5)/(dm+1e-5))| <= ln(60/1e-5) = 15.61 < 16.
#define TBL_N    32768
#define TBL_LO   (-16.0f)
#define TBL_H    (1.0f / 1024.0f)
#define TBL_INVH 1024.0f

// log2(10000)/128
#define L2T128   0.10381025293350249f

__device__ __forceinline__ unsigned bf16_rne(float x) {
    unsigned u = __float_as_uint(x);
    return (u + 0x7fffu + ((u >> 16) & 1u)) >> 16;
}

// tbl[e] = bf16x8{ b[h] + sum_i Ws[i,h] sin(k_i d_e) + Wc[i,h] cos(k_i d_e) }
// One thread per entry; freq index i is wave-uniform -> W rows via s_load (scalar pipe).
__global__ __launch_bounds__(BLK) void dre_build(const float* __restrict__ W,
                                                 const float* __restrict__ b,
                                                 uint4* __restrict__ tbl)
{
    const int e = blockIdx.x * BLK + threadIdx.x;         // 0..32767
    const float delta = TBL_LO + (float)e * TBL_H;

    // rj[j] = 10000^(-j/128), j=0..7 (8 trans ops, once per thread)
    float rj[8];
#pragma unroll
    for (int j = 0; j < 8; ++j) rj[j] = exp2f(-(float)j * L2T128);

    float acc[NH];
#pragma unroll
    for (int h = 0; h < NH; ++h) acc[h] = b[h];           // uniform -> s_load

    for (int i0 = 0; i0 < 128; i0 += 8) {
        const float kb = 100.0f * exp2f(-(float)i0 * L2T128);
        const float dk = delta * kb;
#pragma unroll
        for (int j = 0; j < 8; ++j) {
            const float a = dk * rj[j];                   // |a| <= 1600 rad < 256 rev: v_sin ok
            const float s = __sinf(a);
            const float c = __cosf(a);
            const float* wr = W + (i0 + j) * 2 * NH;      // wave-uniform -> s_load
#pragma unroll
            for (int h = 0; h < NH; ++h) {
                acc[h] = fmaf(s, wr[h],      acc[h]);
                acc[h] = fmaf(c, wr[NH + h], acc[h]);
            }
        }
    }

    uint4 o;
    o.x = bf16_rne(acc[0]) | (bf16_rne(acc[1]) << 16);
    o.y = bf16_rne(acc[2]) | (bf16_rne(acc[3]) << 16);
    o.z = bf16_rne(acc[4]) | (bf16_rne(acc[5]) << 16);
    o.w = bf16_rne(acc[6]) | (bf16_rne(acc[7]) << 16);
    tbl[e] = o;
}

__device__ __forceinline__ float blo(unsigned u) { return __uint_as_float(u << 16); }
__device__ __forceinline__ float bhi(unsigned u) { return __uint_as_float(u & 0xffff0000u); }

// One thread per 4 consecutive hw points: delta -> lerp(bf16 table) -> relu -> float4 stores.
__global__ __launch_bounds__(BLK) void dre_main(const float* __restrict__ pd,
                                                const float* __restrict__ dm,
                                                const uint4* __restrict__ tbl,
                                                float* __restrict__ out)
{
    const int g = blockIdx.x * BLK + threadIdx.x;
    const int p = g * 4;
    if (p >= TOTAL) return;
    const int n  = p / HW_SZ;
    const int hw = p - n * HW_SZ;                          // same n for all 4 points

    const float lp = __logf(fmaxf(pd[n], 0.0f) + 1e-5f);
    const float4 dv = *(const float4*)(dm + hw);
    const float dvs[4] = {dv.x, dv.y, dv.z, dv.w};

    float vout[4][NH];
#pragma unroll
    for (int q = 0; q < 4; ++q) {
        const float delta = lp - __logf(dvs[q] + 1e-5f);
        const float t  = (delta - TBL_LO) * TBL_INVH;
        const float jf = floorf(t);
        int j = (int)jf;
        j = max(0, min(j, TBL_N - 2));
        const float f = t - jf;
        const uint4 ra = tbl[j];                           // row j   (8 bf16)
        const uint4 rb = tbl[j + 1];                       // row j+1 (8 bf16)
        const float a0 = blo(ra.x), a1 = bhi(ra.x), a2 = blo(ra.y), a3 = bhi(ra.y);
        const float a4 = blo(ra.z), a5 = bhi(ra.z), a6 = blo(ra.w), a7 = bhi(ra.w);
        const float b0 = blo(rb.x), b1 = bhi(rb.x), b2 = blo(rb.y), b3 = bhi(rb.y);
        const float b4 = blo(rb.z), b5 = bhi(rb.z), b6 = blo(rb.w), b7 = bhi(rb.w);
        vout[q][0] = fmaxf(fmaf(f, b0 - a0, a0), 0.0f);
        vout[q][1] = fmaxf(fmaf(f, b1 - a1, a1), 0.0f);
        vout[q][2] = fmaxf(fmaf(f, b2 - a2, a2), 0.0f);
        vout[q][3] = fmaxf(fmaf(f, b3 - a3, a3), 0.0f);
        vout[q][4] = fmaxf(fmaf(f, b4 - a4, a4), 0.0f);
        vout[q][5] = fmaxf(fmaf(f, b5 - a5, a5), 0.0f);
        vout[q][6] = fmaxf(fmaf(f, b6 - a6, a6), 0.0f);
        vout[q][7] = fmaxf(fmaf(f, b7 - a7, a7), 0.0f);
    }

#pragma unroll
    for (int h = 0; h < NH; ++h) {
        float4 o = make_float4(vout[0][h], vout[1][h], vout[2][h], vout[3][h]);
        *(float4*)(out + (size_t)h * TOTAL + p) = o;       // p%4==0 -> 16B aligned
    }
}

extern "C" void kernel_launch(void* const* d_in, const int* in_sizes, int n_in,
                              void* d_out, int out_size, void* d_ws, size_t ws_size,
                              hipStream_t stream) {
    const float* pd = (const float*)d_in[0];
    const float* dm = (const float*)d_in[1];
    const float* W  = (const float*)d_in[2];
    const float* b  = (const float*)d_in[3];
    float* out = (float*)d_out;
    uint4* tbl = (uint4*)d_ws;                             // 32768 * 16 B = 512 KB

    dre_build<<<TBL_N / BLK, BLK, 0, stream>>>(W, b, tbl);
    dre_main<<<(TOTAL / 4 + BLK - 1) / BLK, BLK, 0, stream>>>(pd, dm, tbl, out);
}